// Round 9
// baseline (1693.381 us; speedup 1.0000x reference)
//
#include <hip/hip_runtime.h>

typedef __attribute__((ext_vector_type(4))) float f32x4;
typedef __attribute__((ext_vector_type(8))) short short8;
typedef __attribute__((ext_vector_type(2))) unsigned int uint2v;
typedef __attribute__((ext_vector_type(4))) unsigned int uint4v;

#define MFMA_BF16(a,b,c) __builtin_amdgcn_mfma_f32_16x16x32_bf16(a,b,c,0,0,0)

__device__ __forceinline__ unsigned short bf16_of(float f) {
  union { float f; unsigned int u; } v; v.f = f;
  unsigned int r = v.u + 0x7fffu + ((v.u >> 16) & 1u);
  return (unsigned short)(r >> 16);
}

__device__ __forceinline__ unsigned int cvt_pk_bf16(float lo, float hi) {
  unsigned int r;
  asm("v_cvt_pk_bf16_f32 %0, %1, %2" : "=v"(r) : "v"(lo), "v"(hi));
  return r;
}

__device__ __forceinline__ void gload_lds16(const void* g, void* l) {
  __builtin_amdgcn_global_load_lds(
      (const __attribute__((address_space(1))) unsigned int*)g,
      (__attribute__((address_space(3))) unsigned int*)l, 16, 0, 0);
}

// ---------------------------------------------------------------------------
// K1: weight transpose + cast. Wt[n][k] = bf16(W[k][n]) for 4 E x E matrices.
// ---------------------------------------------------------------------------
__global__ __launch_bounds__(256)
void wcast_kernel(const float* __restrict__ W0, const float* __restrict__ W1,
                  const float* __restrict__ W2, const float* __restrict__ W3,
                  unsigned short* __restrict__ wt) {
  __shared__ float tile[64][65];
  const float* W = (blockIdx.z == 0) ? W0 : (blockIdx.z == 1) ? W1
                 : (blockIdx.z == 2) ? W2 : W3;
  unsigned short* Wt = wt + (size_t)blockIdx.z * (1024u * 1024u);
  int k0 = blockIdx.x * 64, n0 = blockIdx.y * 64;
  int t = threadIdx.x, r = t >> 6, c = t & 63;
#pragma unroll
  for (int i = 0; i < 16; ++i)
    tile[r + i * 4][c] = W[(size_t)(k0 + r + i * 4) * 1024 + n0 + c];
  __syncthreads();
#pragma unroll
  for (int i = 0; i < 16; ++i)
    Wt[(size_t)(n0 + r + i * 4) * 1024 + k0 + c] = bf16_of(tile[c][r + i * 4]);
}

// ---------------------------------------------------------------------------
// K2: fused Q/K/V projection GEMM -- proven 2-barrier template, max-occupancy
// parameters. C[65536x1024] = A(f32)[65536x1024] * Bt^T (+bias).
// z=0: relu -> qw [B,H,S,D]; z=1: relu -> kw; z=2: vw [B,H,D,S] transposed.
// BM=BN=128, BK=64, 256 thr / 4 waves (2m x 2n), wave tile 64x64 (32 MFMA/it).
// Single-buffer LDS 32KB (A 16KB ds_write-staged + B 16KB glds) -> 4-5
// blocks/CU co-resident = 4-5 independent barrier domains hiding the drain.
// LDS rows 128B: phys 16B slot = slot ^ (row&7) on both write & read paths;
// glds keeps linear dest + same involution pre-applied to the global source.
// ---------------------------------------------------------------------------
__global__ __launch_bounds__(256, 4)
void gemm_qkv(const float* __restrict__ Aq, const float* __restrict__ Ak,
              const float* __restrict__ Av, const unsigned short* __restrict__ wt,
              const float* __restrict__ bq, const float* __restrict__ bk,
              const float* __restrict__ bv, unsigned short* __restrict__ qw,
              unsigned short* __restrict__ kw, unsigned short* __restrict__ vw) {
  __shared__ unsigned short ldsA[128 * 64];  // 16KB
  __shared__ unsigned short ldsB[128 * 64];  // 16KB

  int z = blockIdx.z;
  const float* Af = (z == 0) ? Aq : (z == 1) ? Ak : Av;
  const unsigned short* Bt = wt + (size_t)z * 1048576;
  const float* bias = (z == 0) ? bq : (z == 1) ? bk : bv;
  unsigned short* C = (z == 0) ? qw : (z == 1) ? kw : vw;

  int bid = blockIdx.x;
  // XCD swizzle (4096 blocks = 8 XCDs x 512): XCD x gets 64 contiguous
  // m-tiles; the 8 n-tiles of one m-tile are adjacent on that XCD.
  int mt = (bid & 7) * 64 + (bid >> 6);
  int nt = (bid >> 3) & 7;
  int m0 = mt * 128, n0 = nt * 128;

  int tid = threadIdx.x;
  int w = tid >> 6, l = tid & 63;
  int wm = w >> 1, wn = w & 1;
  int li = l & 15, grp = l >> 4;

  f32x4 acc[4][4] = {};

  // glds lane map: chunk c covers 8 rows (1KB); lane l -> row 8c+(l>>3),
  // linear dest slot l&7; source seg pre-swizzled = (l&7)^(row&7).
  int grow = l >> 3;
  int gseg = (l & 7) ^ grow;

  // f32-A staging: thread covers row rA = tid>>1 (0..127), 32 f32 at q*32.
  int rA = tid >> 1, q = tid & 1;

  f32x4 areg[8];
  auto loadA = [&](int kt) {
#pragma unroll
    for (int j = 0; j < 8; ++j)
      areg[j] = *(const f32x4*)(Af + (size_t)(m0 + rA) * 1024 + kt * 64 + q * 32 + j * 4);
  };
  auto writeA = [&]() {
#pragma unroll
    for (int p = 0; p < 4; ++p) {
      uint4v wv;
      wv[0] = cvt_pk_bf16(areg[2 * p][0], areg[2 * p][1]);
      wv[1] = cvt_pk_bf16(areg[2 * p][2], areg[2 * p][3]);
      wv[2] = cvt_pk_bf16(areg[2 * p + 1][0], areg[2 * p + 1][1]);
      wv[3] = cvt_pk_bf16(areg[2 * p + 1][2], areg[2 * p + 1][3]);
      // thread covers 16B segs 4q+p; phys = seg ^ (row&7)
      *(uint4v*)((char*)ldsA + rA * 128 + (((4 * q + p) ^ (rA & 7)) << 4)) = wv;
    }
  };

  loadA(0);

  for (int kt = 0; kt < 16; ++kt) {
    int k0 = kt * 64;
    // ---- stage A (cvt + swizzled ds_write) ----
    writeA();
    // ---- stage B (glds): 16 chunks, 4 per wave ----
#pragma unroll
    for (int i = 0; i < 4; ++i) {
      int c = w * 4 + i;
      gload_lds16(Bt + (size_t)(n0 + 8 * c + grow) * 1024 + k0 + gseg * 8,
                  (char*)ldsB + c * 1024);
    }
    // ---- prefetch next A ----
    if (kt < 15) loadA(kt + 1);
    __syncthreads();
    // ---- compute: 2 K-subtiles, 16 MFMA each ----
#pragma unroll
    for (int ks = 0; ks < 2; ++ks) {
      short8 af[4], bf[4];
#pragma unroll
      for (int mi = 0; mi < 4; ++mi) {
        int row = wm * 64 + mi * 16 + li;
        af[mi] = *(const short8*)((const char*)ldsA + row * 128 +
                                  (((ks * 4 + grp) ^ (row & 7)) << 4));
      }
#pragma unroll
      for (int ni = 0; ni < 4; ++ni) {
        int row = wn * 64 + ni * 16 + li;
        bf[ni] = *(const short8*)((const char*)ldsB + row * 128 +
                                  (((ks * 4 + grp) ^ (row & 7)) << 4));
      }
#pragma unroll
      for (int mi = 0; mi < 4; ++mi)
#pragma unroll
        for (int ni = 0; ni < 4; ++ni)
          acc[mi][ni] = MFMA_BF16(af[mi], bf[ni], acc[mi][ni]);
    }
    __syncthreads();
  }

  // ---- epilogue ----
  int mrow0 = m0 + wm * 64;   // 64-aligned -> single batch b per wave
  int ncol0 = n0 + wn * 64;   // 64-aligned -> single head h per wave
  float bvv[4];
#pragma unroll
  for (int ni = 0; ni < 4; ++ni) bvv[ni] = bias[ncol0 + ni * 16 + li];

  int b = mrow0 >> 6, h = ncol0 >> 6;
  unsigned short* base = C + (size_t)b * 65536 + (size_t)h * 4096;
  if (z < 2) {  // Q/K: ReLU, [b][h][s][d]
#pragma unroll
    for (int mi = 0; mi < 4; ++mi)
#pragma unroll
      for (int ni = 0; ni < 4; ++ni)
#pragma unroll
        for (int j = 0; j < 4; ++j) {
          float v = acc[mi][ni][j] + bvv[ni];
          v = fmaxf(v, 0.0f);
          base[(mi * 16 + grp * 4 + j) * 64 + ni * 16 + li] = bf16_of(v);
        }
  } else {  // V: transposed [b][h][d][s]
#pragma unroll
    for (int mi = 0; mi < 4; ++mi)
#pragma unroll
      for (int ni = 0; ni < 4; ++ni) {
        uint2v pk;
        pk.x = cvt_pk_bf16(acc[mi][ni][0] + bvv[ni], acc[mi][ni][1] + bvv[ni]);
        pk.y = cvt_pk_bf16(acc[mi][ni][2] + bvv[ni], acc[mi][ni][3] + bvv[ni]);
        *(uint2v*)(base + (ni * 16 + li) * 64 + mi * 16 + grp * 4) = pk;
      }
  }
}

// ---------------------------------------------------------------------------
// K2b: output GEMM -- same max-occupancy template, glds both operands.
// C[65536x1024](f32) = A(bf16) * Bt^T + bo.
// BM=BN=128, BK=64, 256 thr / 4 waves (2x2), wave tile 64x64, LDS 32KB.
// ---------------------------------------------------------------------------
__global__ __launch_bounds__(256, 4)
void gemm_out(const unsigned short* __restrict__ Ab, const unsigned short* __restrict__ Bt,
              const float* __restrict__ bias, float* __restrict__ C) {
  __shared__ unsigned short ldsA[128 * 64];  // 16KB
  __shared__ unsigned short ldsB[128 * 64];  // 16KB

  int bid = blockIdx.x;
  int mt = (bid & 7) * 64 + (bid >> 6);
  int nt = (bid >> 3) & 7;
  int m0 = mt * 128, n0 = nt * 128;

  int tid = threadIdx.x;
  int w = tid >> 6, l = tid & 63;
  int wm = w >> 1, wn = w & 1;
  int li = l & 15, grp = l >> 4;

  f32x4 acc[4][4] = {};

  int grow = l >> 3;
  int gseg = (l & 7) ^ grow;

  for (int kt = 0; kt < 16; ++kt) {
    int k0 = kt * 64;
#pragma unroll
    for (int i = 0; i < 4; ++i) {
      int c = w * 4 + i;
      gload_lds16(Ab + (size_t)(m0 + 8 * c + grow) * 1024 + k0 + gseg * 8,
                  (char*)ldsA + c * 1024);
    }
#pragma unroll
    for (int i = 0; i < 4; ++i) {
      int c = w * 4 + i;
      gload_lds16(Bt + (size_t)(n0 + 8 * c + grow) * 1024 + k0 + gseg * 8,
                  (char*)ldsB + c * 1024);
    }
    __syncthreads();
#pragma unroll
    for (int ks = 0; ks < 2; ++ks) {
      short8 af[4], bf[4];
#pragma unroll
      for (int mi = 0; mi < 4; ++mi) {
        int row = wm * 64 + mi * 16 + li;
        af[mi] = *(const short8*)((const char*)ldsA + row * 128 +
                                  (((ks * 4 + grp) ^ (row & 7)) << 4));
      }
#pragma unroll
      for (int ni = 0; ni < 4; ++ni) {
        int row = wn * 64 + ni * 16 + li;
        bf[ni] = *(const short8*)((const char*)ldsB + row * 128 +
                                  (((ks * 4 + grp) ^ (row & 7)) << 4));
      }
#pragma unroll
      for (int mi = 0; mi < 4; ++mi)
#pragma unroll
        for (int ni = 0; ni < 4; ++ni)
          acc[mi][ni] = MFMA_BF16(af[mi], bf[ni], acc[mi][ni]);
    }
    __syncthreads();
  }

  int mrow0 = m0 + wm * 64;
  int ncol0 = n0 + wn * 64;
  float bvv[4];
#pragma unroll
  for (int ni = 0; ni < 4; ++ni) bvv[ni] = bias[ncol0 + ni * 16 + li];
#pragma unroll
  for (int mi = 0; mi < 4; ++mi)
#pragma unroll
    for (int ni = 0; ni < 4; ++ni)
#pragma unroll
      for (int j = 0; j < 4; ++j)
        C[(size_t)(mrow0 + mi * 16 + grp * 4 + j) * 1024 + ncol0 + ni * 16 + li] =
            acc[mi][ni][j] + bvv[ni];
}

// ---------------------------------------------------------------------------
// K3: attention. One wave per (b,h). Q,K: [b][h][s][d] bf16 (ReLU'd, biased),
// V: [b][h][d][s] bf16. Out: [b][s][h][d] bf16.
// ---------------------------------------------------------------------------
__global__ __launch_bounds__(64)
void attn_kernel(const unsigned short* __restrict__ qw,
                 const unsigned short* __restrict__ kw,
                 const unsigned short* __restrict__ vw,
                 unsigned short* __restrict__ aw) {
  __shared__ unsigned short p_lds[64 * 72];
  int bh = blockIdx.x;
  int b = bh >> 4, h = bh & 15;
  int l = threadIdx.x;
  int li = l & 15, grp = l >> 4;
  const unsigned short* qb = qw + (size_t)bh * 4096;
  const unsigned short* kb = kw + (size_t)bh * 4096;
  const unsigned short* vb = vw + (size_t)bh * 4096;

  short8 aq[4][2], bk_[4][2];
#pragma unroll
  for (int mi = 0; mi < 4; ++mi)
#pragma unroll
    for (int ks = 0; ks < 2; ++ks) {
      aq[mi][ks]  = *(const short8*)(qb + (mi * 16 + li) * 64 + ks * 32 + grp * 8);
      bk_[mi][ks] = *(const short8*)(kb + (mi * 16 + li) * 64 + ks * 32 + grp * 8);
    }

  f32x4 sf[4][4];
#pragma unroll
  for (int mi = 0; mi < 4; ++mi)
#pragma unroll
    for (int ni = 0; ni < 4; ++ni) {
      f32x4 t = {};
      t = MFMA_BF16(aq[mi][0], bk_[ni][0], t);
      t = MFMA_BF16(aq[mi][1], bk_[ni][1], t);
      sf[mi][ni] = t;
    }

#pragma unroll
  for (int mi = 0; mi < 4; ++mi) {
#pragma unroll
    for (int j = 0; j < 4; ++j) {
      int row = mi * 16 + grp * 4 + j;
      float mx = -1e30f;
#pragma unroll
      for (int ni = 0; ni < 4; ++ni) {
        int col = ni * 16 + li;
        float v = sf[mi][ni][j] * 0.125f;
        v = (col <= row) ? v : -1e30f;
        sf[mi][ni][j] = v;
        mx = fmaxf(mx, v);
      }
#pragma unroll
      for (int sh = 1; sh < 16; sh <<= 1) mx = fmaxf(mx, __shfl_xor(mx, sh, 64));
      float sum = 0.0f;
#pragma unroll
      for (int ni = 0; ni < 4; ++ni) {
        float e = __expf(sf[mi][ni][j] - mx);
        sf[mi][ni][j] = e;
        sum += e;
      }
#pragma unroll
      for (int sh = 1; sh < 16; sh <<= 1) sum += __shfl_xor(sum, sh, 64);
      float rr = 1.0f / sum;
#pragma unroll
      for (int ni = 0; ni < 4; ++ni) sf[mi][ni][j] *= rr;
    }
  }

#pragma unroll
  for (int mi = 0; mi < 4; ++mi)
#pragma unroll
    for (int ni = 0; ni < 4; ++ni)
#pragma unroll
      for (int j = 0; j < 4; ++j)
        p_lds[(mi * 16 + grp * 4 + j) * 72 + ni * 16 + li] = bf16_of(sf[mi][ni][j]);
  __syncthreads();

  short8 pa[4][2], bv_[4][2];
#pragma unroll
  for (int mi = 0; mi < 4; ++mi)
#pragma unroll
    for (int ks = 0; ks < 2; ++ks)
      pa[mi][ks] = *(const short8*)(p_lds + (mi * 16 + li) * 72 + ks * 32 + grp * 8);
#pragma unroll
  for (int ni = 0; ni < 4; ++ni)
#pragma unroll
    for (int ks = 0; ks < 2; ++ks)
      bv_[ni][ks] = *(const short8*)(vb + (ni * 16 + li) * 64 + ks * 32 + grp * 8);

  f32x4 of[4][4];
#pragma unroll
  for (int mi = 0; mi < 4; ++mi)
#pragma unroll
    for (int ni = 0; ni < 4; ++ni) {
      f32x4 t = {};
      t = MFMA_BF16(pa[mi][0], bv_[ni][0], t);
      t = MFMA_BF16(pa[mi][1], bv_[ni][1], t);
      of[mi][ni] = t;
    }

  unsigned short* ab = aw + (size_t)b * 65536 + (size_t)h * 64;
#pragma unroll
  for (int mi = 0; mi < 4; ++mi)
#pragma unroll
    for (int ni = 0; ni < 4; ++ni)
#pragma unroll
      for (int j = 0; j < 4; ++j)
        ab[(size_t)(mi * 16 + grp * 4 + j) * 1024 + ni * 16 + li] = bf16_of(of[mi][ni][j]);
}

// ---------------------------------------------------------------------------
extern "C" void kernel_launch(void* const* d_in, const int* in_sizes, int n_in,
                              void* d_out, int out_size, void* d_ws, size_t ws_size,
                              hipStream_t stream) {
  (void)in_sizes; (void)n_in; (void)out_size; (void)ws_size;
  const float* query = (const float*)d_in[0];
  const float* key   = (const float*)d_in[1];
  const float* value = (const float*)d_in[2];
  const float* Wq = (const float*)d_in[3];
  const float* bq = (const float*)d_in[4];
  const float* Wk = (const float*)d_in[5];
  const float* bk = (const float*)d_in[6];
  const float* Wv = (const float*)d_in[7];
  const float* bv = (const float*)d_in[8];
  const float* Wo = (const float*)d_in[9];
  const float* bo = (const float*)d_in[10];
  float* out = (float*)d_out;

  unsigned short* wt = (unsigned short*)d_ws;
  const size_t NE = (size_t)67108864;  // B*S*E
  unsigned short* qw = wt + (size_t)4 * 1024 * 1024;
  unsigned short* kw = qw + NE;
  unsigned short* vw = kw + NE;
  unsigned short* aw = vw + NE;

  wcast_kernel<<<dim3(16, 16, 4), 256, 0, stream>>>(Wq, Wk, Wv, Wo, wt);
  gemm_qkv<<<dim3(4096, 1, 3), 256, 0, stream>>>(query, key, value, wt,
                                                 bq, bk, bv, qw, kw, vw);
  attn_kernel<<<dim3(16384), 64, 0, stream>>>(qw, kw, vw, aw);
  gemm_out<<<dim3(4096), 256, 0, stream>>>(aw, wt + (size_t)3 * 1048576, bo, out);
}

// Round 10
// 829.950 us; speedup vs baseline: 2.0403x; 2.0403x over previous
//
#include <hip/hip_runtime.h>

typedef __attribute__((ext_vector_type(4))) float f32x4;
typedef __attribute__((ext_vector_type(8))) short short8;
typedef __attribute__((ext_vector_type(2))) unsigned int uint2v;
typedef __attribute__((ext_vector_type(4))) unsigned int uint4v;

#define MFMA_BF16(a,b,c) __builtin_amdgcn_mfma_f32_16x16x32_bf16(a,b,c,0,0,0)

__device__ __forceinline__ unsigned short bf16_of(float f) {
  union { float f; unsigned int u; } v; v.f = f;
  unsigned int r = v.u + 0x7fffu + ((v.u >> 16) & 1u);
  return (unsigned short)(r >> 16);
}

__device__ __forceinline__ unsigned int cvt_pk_bf16(float lo, float hi) {
  unsigned int r;
  asm("v_cvt_pk_bf16_f32 %0, %1, %2" : "=v"(r) : "v"(lo), "v"(hi));
  return r;
}

__device__ __forceinline__ void gload_lds16(const void* g, void* l) {
  __builtin_amdgcn_global_load_lds(
      (const __attribute__((address_space(1))) unsigned int*)g,
      (__attribute__((address_space(3))) unsigned int*)l, 16, 0, 0);
}

// ---------------------------------------------------------------------------
// K1: weight transpose + cast. Wt[n][k] = bf16(W[k][n]) for 4 E x E matrices.
// ---------------------------------------------------------------------------
__global__ __launch_bounds__(256)
void wcast_kernel(const float* __restrict__ W0, const float* __restrict__ W1,
                  const float* __restrict__ W2, const float* __restrict__ W3,
                  unsigned short* __restrict__ wt) {
  __shared__ float tile[64][65];
  const float* W = (blockIdx.z == 0) ? W0 : (blockIdx.z == 1) ? W1
                 : (blockIdx.z == 2) ? W2 : W3;
  unsigned short* Wt = wt + (size_t)blockIdx.z * (1024u * 1024u);
  int k0 = blockIdx.x * 64, n0 = blockIdx.y * 64;
  int t = threadIdx.x, r = t >> 6, c = t & 63;
#pragma unroll
  for (int i = 0; i < 16; ++i)
    tile[r + i * 4][c] = W[(size_t)(k0 + r + i * 4) * 1024 + n0 + c];
  __syncthreads();
#pragma unroll
  for (int i = 0; i < 16; ++i)
    Wt[(size_t)(n0 + r + i * 4) * 1024 + k0 + c] = bf16_of(tile[c][r + i * 4]);
}

// ---------------------------------------------------------------------------
// K2: fused Q/K/V projection GEMM (r7-proven config; A-load reorder).
// C[65536x1024] = A(f32)[65536x1024] * Bt^T (+bias).
// z=0: relu -> qw [B,H,S,D]; z=1: relu -> kw; z=2: vw [B,H,D,S] transposed.
// BM=128, BN=256, BK=64, 512 thr / 8 waves (2m x 4n), wave tile 64x64.
// Single-buffer LDS 48KB, both __syncthreads kept. CHANGE vs r7: the A
// register prefetch for kt+1 is issued AFTER the first barrier (not before),
// so the barrier's vmcnt(0) drains only the L2-hot B-glds; the A-loads'
// latency is covered by the compute phase before their use (writeA, next it).
// LDS rows 128B: phys 16B slot = slot ^ (row&7) on both write & read paths;
// glds keeps linear dest + same involution pre-applied to the global source.
// ---------------------------------------------------------------------------
__global__ __launch_bounds__(512, 4)
void gemm_qkv(const float* __restrict__ Aq, const float* __restrict__ Ak,
              const float* __restrict__ Av, const unsigned short* __restrict__ wt,
              const float* __restrict__ bq, const float* __restrict__ bk,
              const float* __restrict__ bv, unsigned short* __restrict__ qw,
              unsigned short* __restrict__ kw, unsigned short* __restrict__ vw) {
  __shared__ unsigned short ldsA[128 * 64];  // 16KB
  __shared__ unsigned short ldsB[256 * 64];  // 32KB

  int z = blockIdx.z;
  const float* Af = (z == 0) ? Aq : (z == 1) ? Ak : Av;
  const unsigned short* Bt = wt + (size_t)z * 1048576;
  const float* bias = (z == 0) ? bq : (z == 1) ? bk : bv;
  unsigned short* C = (z == 0) ? qw : (z == 1) ? kw : vw;

  int bid = blockIdx.x;
  // XCD swizzle (2048 blocks = 8 XCDs x 256): XCD x gets 64 contiguous
  // m-tiles; the 4 n-tiles of one m-tile are adjacent on that XCD.
  int mt = (bid & 7) * 64 + (bid >> 5);
  int nt = (bid >> 3) & 3;
  int m0 = mt * 128, n0 = nt * 256;

  int tid = threadIdx.x;
  int w = tid >> 6, l = tid & 63;
  int wm = w >> 2, wn = w & 3;
  int li = l & 15, grp = l >> 4;

  f32x4 acc[4][4] = {};

  // glds lane map: chunk c covers 8 rows (1KB); lane l -> row 8c+(l>>3),
  // linear dest slot l&7; source seg pre-swizzled = (l&7)^(row&7).
  int grow = l >> 3;
  int gseg = (l & 7) ^ grow;

  // f32-A staging: thread covers row rA = tid>>2 (0..127), 16 f32 at q*16.
  int rA = tid >> 2, q = tid & 3;

  f32x4 areg[4];
  auto loadA = [&](int kt) {
#pragma unroll
    for (int j = 0; j < 4; ++j)
      areg[j] = *(const f32x4*)(Af + (size_t)(m0 + rA) * 1024 + kt * 64 + q * 16 + j * 4);
  };

  loadA(0);

  for (int kt = 0; kt < 16; ++kt) {
    int k0 = kt * 64;
    // ---- stage A (cvt + swizzled ds_write; areg loaded one iter ago) ----
    {
      uint4v w0, w1;
      w0[0] = cvt_pk_bf16(areg[0][0], areg[0][1]);
      w0[1] = cvt_pk_bf16(areg[0][2], areg[0][3]);
      w0[2] = cvt_pk_bf16(areg[1][0], areg[1][1]);
      w0[3] = cvt_pk_bf16(areg[1][2], areg[1][3]);
      w1[0] = cvt_pk_bf16(areg[2][0], areg[2][1]);
      w1[1] = cvt_pk_bf16(areg[2][2], areg[2][3]);
      w1[2] = cvt_pk_bf16(areg[3][0], areg[3][1]);
      w1[3] = cvt_pk_bf16(areg[3][2], areg[3][3]);
      *(uint4v*)((char*)ldsA + rA * 128 + (((2 * q)     ^ (rA & 7)) << 4)) = w0;
      *(uint4v*)((char*)ldsA + rA * 128 + (((2 * q + 1) ^ (rA & 7)) << 4)) = w1;
    }
    // ---- stage B (glds, L2-hot weight panel) ----
#pragma unroll
    for (int i = 0; i < 4; ++i) {
      int c = w * 4 + i;
      gload_lds16(Bt + (size_t)(n0 + 8 * c + grow) * 1024 + k0 + gseg * 8,
                  (char*)ldsB + c * 1024);
    }
    __syncthreads();   // drains glds only (A-prefetch not yet issued)
    // ---- A prefetch for kt+1: issued here, used after next barrier ----
    if (kt < 15) {
      loadA(kt + 1);
      __builtin_amdgcn_sched_barrier(0);  // don't sink into compute
    }
    // ---- compute: 2 K-subtiles, 16 MFMA each ----
#pragma unroll
    for (int ks = 0; ks < 2; ++ks) {
      short8 af[4], bf[4];
#pragma unroll
      for (int mi = 0; mi < 4; ++mi) {
        int row = wm * 64 + mi * 16 + li;
        af[mi] = *(const short8*)((const char*)ldsA + row * 128 +
                                  (((ks * 4 + grp) ^ (row & 7)) << 4));
      }
#pragma unroll
      for (int ni = 0; ni < 4; ++ni) {
        int row = wn * 64 + ni * 16 + li;
        bf[ni] = *(const short8*)((const char*)ldsB + row * 128 +
                                  (((ks * 4 + grp) ^ (row & 7)) << 4));
      }
#pragma unroll
      for (int mi = 0; mi < 4; ++mi)
#pragma unroll
        for (int ni = 0; ni < 4; ++ni)
          acc[mi][ni] = MFMA_BF16(af[mi], bf[ni], acc[mi][ni]);
    }
    __syncthreads();
  }

  // ---- epilogue ----
  int mrow0 = m0 + wm * 64;   // 64-aligned -> single batch b per wave
  int ncol0 = n0 + wn * 64;   // 64-aligned -> single head h per wave
  float bvv[4];
#pragma unroll
  for (int ni = 0; ni < 4; ++ni) bvv[ni] = bias[ncol0 + ni * 16 + li];

  int b = mrow0 >> 6, h = ncol0 >> 6;
  unsigned short* base = C + (size_t)b * 65536 + (size_t)h * 4096;
  if (z < 2) {  // Q/K: ReLU, [b][h][s][d]
#pragma unroll
    for (int mi = 0; mi < 4; ++mi)
#pragma unroll
      for (int ni = 0; ni < 4; ++ni)
#pragma unroll
        for (int j = 0; j < 4; ++j) {
          float v = acc[mi][ni][j] + bvv[ni];
          v = fmaxf(v, 0.0f);
          base[(mi * 16 + grp * 4 + j) * 64 + ni * 16 + li] = bf16_of(v);
        }
  } else {  // V: transposed [b][h][d][s]
#pragma unroll
    for (int mi = 0; mi < 4; ++mi)
#pragma unroll
      for (int ni = 0; ni < 4; ++ni) {
        uint2v pk;
        pk.x = cvt_pk_bf16(acc[mi][ni][0] + bvv[ni], acc[mi][ni][1] + bvv[ni]);
        pk.y = cvt_pk_bf16(acc[mi][ni][2] + bvv[ni], acc[mi][ni][3] + bvv[ni]);
        *(uint2v*)(base + (ni * 16 + li) * 64 + mi * 16 + grp * 4) = pk;
      }
  }
}

// ---------------------------------------------------------------------------
// K2b: output GEMM -- r7 form (single-buffer, __syncthreads, glds both).
// C[65536x1024](f32) = A(bf16) * Bt^T + bo.  BM=128, BN=256, BK=64, 512 thr,
// 8 waves (2m x 4n), wave tile 64x64, LDS 48KB.
// ---------------------------------------------------------------------------
__global__ __launch_bounds__(512, 4)
void gemm_out(const unsigned short* __restrict__ Ab, const unsigned short* __restrict__ Bt,
              const float* __restrict__ bias, float* __restrict__ C) {
  __shared__ unsigned short ldsA[128 * 64];  // 16KB
  __shared__ unsigned short ldsB[256 * 64];  // 32KB

  int bid = blockIdx.x;
  int mt = (bid & 7) * 64 + (bid >> 5);
  int nt = (bid >> 3) & 3;
  int m0 = mt * 128, n0 = nt * 256;

  int tid = threadIdx.x;
  int w = tid >> 6, l = tid & 63;
  int wm = w >> 2, wn = w & 3;
  int li = l & 15, grp = l >> 4;

  f32x4 acc[4][4] = {};

  int grow = l >> 3;
  int gseg = (l & 7) ^ grow;

  for (int kt = 0; kt < 16; ++kt) {
    int k0 = kt * 64;
#pragma unroll
    for (int i = 0; i < 2; ++i) {
      int c = w * 2 + i;
      gload_lds16(Ab + (size_t)(m0 + 8 * c + grow) * 1024 + k0 + gseg * 8,
                  (char*)ldsA + c * 1024);
    }
#pragma unroll
    for (int i = 0; i < 4; ++i) {
      int c = w * 4 + i;
      gload_lds16(Bt + (size_t)(n0 + 8 * c + grow) * 1024 + k0 + gseg * 8,
                  (char*)ldsB + c * 1024);
    }
    __syncthreads();
#pragma unroll
    for (int ks = 0; ks < 2; ++ks) {
      short8 af[4], bf[4];
#pragma unroll
      for (int mi = 0; mi < 4; ++mi) {
        int row = wm * 64 + mi * 16 + li;
        af[mi] = *(const short8*)((const char*)ldsA + row * 128 +
                                  (((ks * 4 + grp) ^ (row & 7)) << 4));
      }
#pragma unroll
      for (int ni = 0; ni < 4; ++ni) {
        int row = wn * 64 + ni * 16 + li;
        bf[ni] = *(const short8*)((const char*)ldsB + row * 128 +
                                  (((ks * 4 + grp) ^ (row & 7)) << 4));
      }
#pragma unroll
      for (int mi = 0; mi < 4; ++mi)
#pragma unroll
        for (int ni = 0; ni < 4; ++ni)
          acc[mi][ni] = MFMA_BF16(af[mi], bf[ni], acc[mi][ni]);
    }
    __syncthreads();
  }

  int mrow0 = m0 + wm * 64;
  int ncol0 = n0 + wn * 64;
  float bvv[4];
#pragma unroll
  for (int ni = 0; ni < 4; ++ni) bvv[ni] = bias[ncol0 + ni * 16 + li];
#pragma unroll
  for (int mi = 0; mi < 4; ++mi)
#pragma unroll
    for (int ni = 0; ni < 4; ++ni)
#pragma unroll
      for (int j = 0; j < 4; ++j)
        C[(size_t)(mrow0 + mi * 16 + grp * 4 + j) * 1024 + ncol0 + ni * 16 + li] =
            acc[mi][ni][j] + bvv[ni];
}

// ---------------------------------------------------------------------------
// K3: attention. One wave per (b,h). Q,K: [b][h][s][d] bf16 (ReLU'd, biased),
// V: [b][h][d][s] bf16. Out: [b][s][h][d] bf16.
// ---------------------------------------------------------------------------
__global__ __launch_bounds__(64)
void attn_kernel(const unsigned short* __restrict__ qw,
                 const unsigned short* __restrict__ kw,
                 const unsigned short* __restrict__ vw,
                 unsigned short* __restrict__ aw) {
  __shared__ unsigned short p_lds[64 * 72];
  int bh = blockIdx.x;
  int b = bh >> 4, h = bh & 15;
  int l = threadIdx.x;
  int li = l & 15, grp = l >> 4;
  const unsigned short* qb = qw + (size_t)bh * 4096;
  const unsigned short* kb = kw + (size_t)bh * 4096;
  const unsigned short* vb = vw + (size_t)bh * 4096;

  short8 aq[4][2], bk_[4][2];
#pragma unroll
  for (int mi = 0; mi < 4; ++mi)
#pragma unroll
    for (int ks = 0; ks < 2; ++ks) {
      aq[mi][ks]  = *(const short8*)(qb + (mi * 16 + li) * 64 + ks * 32 + grp * 8);
      bk_[mi][ks] = *(const short8*)(kb + (mi * 16 + li) * 64 + ks * 32 + grp * 8);
    }

  f32x4 sf[4][4];
#pragma unroll
  for (int mi = 0; mi < 4; ++mi)
#pragma unroll
    for (int ni = 0; ni < 4; ++ni) {
      f32x4 t = {};
      t = MFMA_BF16(aq[mi][0], bk_[ni][0], t);
      t = MFMA_BF16(aq[mi][1], bk_[ni][1], t);
      sf[mi][ni] = t;
    }

#pragma unroll
  for (int mi = 0; mi < 4; ++mi) {
#pragma unroll
    for (int j = 0; j < 4; ++j) {
      int row = mi * 16 + grp * 4 + j;
      float mx = -1e30f;
#pragma unroll
      for (int ni = 0; ni < 4; ++ni) {
        int col = ni * 16 + li;
        float v = sf[mi][ni][j] * 0.125f;
        v = (col <= row) ? v : -1e30f;
        sf[mi][ni][j] = v;
        mx = fmaxf(mx, v);
      }
#pragma unroll
      for (int sh = 1; sh < 16; sh <<= 1) mx = fmaxf(mx, __shfl_xor(mx, sh, 64));
      float sum = 0.0f;
#pragma unroll
      for (int ni = 0; ni < 4; ++ni) {
        float e = __expf(sf[mi][ni][j] - mx);
        sf[mi][ni][j] = e;
        sum += e;
      }
#pragma unroll
      for (int sh = 1; sh < 16; sh <<= 1) sum += __shfl_xor(sum, sh, 64);
      float rr = 1.0f / sum;
#pragma unroll
      for (int ni = 0; ni < 4; ++ni) sf[mi][ni][j] *= rr;
    }
  }

#pragma unroll
  for (int mi = 0; mi < 4; ++mi)
#pragma unroll
    for (int ni = 0; ni < 4; ++ni)
#pragma unroll
      for (int j = 0; j < 4; ++j)
        p_lds[(mi * 16 + grp * 4 + j) * 72 + ni * 16 + li] = bf16_of(sf[mi][ni][j]);
  __syncthreads();

  short8 pa[4][2], bv_[4][2];
#pragma unroll
  for (int mi = 0; mi < 4; ++mi)
#pragma unroll
    for (int ks = 0; ks < 2; ++ks)
      pa[mi][ks] = *(const short8*)(p_lds + (mi * 16 + li) * 72 + ks * 32 + grp * 8);
#pragma unroll
  for (int ni = 0; ni < 4; ++ni)
#pragma unroll
    for (int ks = 0; ks < 2; ++ks)
      bv_[ni][ks] = *(const short8*)(vb + (ni * 16 + li) * 64 + ks * 32 + grp * 8);

  f32x4 of[4][4];
#pragma unroll
  for (int mi = 0; mi < 4; ++mi)
#pragma unroll
    for (int ni = 0; ni < 4; ++ni) {
      f32x4 t = {};
      t = MFMA_BF16(pa[mi][0], bv_[ni][0], t);
      t = MFMA_BF16(pa[mi][1], bv_[ni][1], t);
      of[mi][ni] = t;
    }

  unsigned short* ab = aw + (size_t)b * 65536 + (size_t)h * 64;
#pragma unroll
  for (int mi = 0; mi < 4; ++mi)
#pragma unroll
    for (int ni = 0; ni < 4; ++ni)
#pragma unroll
      for (int j = 0; j < 4; ++j)
        ab[(size_t)(mi * 16 + grp * 4 + j) * 1024 + ni * 16 + li] = bf16_of(of[mi][ni][j]);
}

// ---------------------------------------------------------------------------
extern "C" void kernel_launch(void* const* d_in, const int* in_sizes, int n_in,
                              void* d_out, int out_size, void* d_ws, size_t ws_size,
                              hipStream_t stream) {
  (void)in_sizes; (void)n_in; (void)out_size; (void)ws_size;
  const float* query = (const float*)d_in[0];
  const float* key   = (const float*)d_in[1];
  const float* value = (const float*)d_in[2];
  const float* Wq = (const float*)d_in[3];
  const float* bq = (const float*)d_in[4];
  const float* Wk = (const float*)d_in[5];
  const float* bk = (const float*)d_in[6];
  const float* Wv = (const float*)d_in[7];
  const float* bv = (const float*)d_in[8];
  const float* Wo = (const float*)d_in[9];
  const float* bo = (const float*)d_in[10];
  float* out = (float*)d_out;

  unsigned short* wt = (unsigned short*)d_ws;
  const size_t NE = (size_t)67108864;  // B*S*E
  unsigned short* qw = wt + (size_t)4 * 1024 * 1024;
  unsigned short* kw = qw + NE;
  unsigned short* vw = kw + NE;
  unsigned short* aw = vw + NE;

  wcast_kernel<<<dim3(16, 16, 4), 256, 0, stream>>>(Wq, Wk, Wv, Wo, wt);
  gemm_qkv<<<dim3(2048, 1, 3), 512, 0, stream>>>(query, key, value, wt,
                                                 bq, bk, bv, qw, kw, vw);
  attn_kernel<<<dim3(16384), 64, 0, stream>>>(qw, kw, vw, aw);
  gemm_out<<<dim3(2048), 512, 0, stream>>>(aw, wt + (size_t)3 * 1048576, bo, out);
}

// Round 11
// 818.420 us; speedup vs baseline: 2.0691x; 1.0141x over previous
//
#include <hip/hip_runtime.h>

typedef __attribute__((ext_vector_type(4))) float f32x4;
typedef __attribute__((ext_vector_type(8))) short short8;
typedef __attribute__((ext_vector_type(2))) unsigned int uint2v;
typedef __attribute__((ext_vector_type(4))) unsigned int uint4v;

#define MFMA_BF16(a,b,c) __builtin_amdgcn_mfma_f32_16x16x32_bf16(a,b,c,0,0,0)

__device__ __forceinline__ unsigned short bf16_of(float f) {
  union { float f; unsigned int u; } v; v.f = f;
  unsigned int r = v.u + 0x7fffu + ((v.u >> 16) & 1u);
  return (unsigned short)(r >> 16);
}

__device__ __forceinline__ unsigned int cvt_pk_bf16(float lo, float hi) {
  unsigned int r;
  asm("v_cvt_pk_bf16_f32 %0, %1, %2" : "=v"(r) : "v"(lo), "v"(hi));
  return r;
}

__device__ __forceinline__ void gload_lds16(const void* g, void* l) {
  __builtin_amdgcn_global_load_lds(
      (const __attribute__((address_space(1))) unsigned int*)g,
      (__attribute__((address_space(3))) unsigned int*)l, 16, 0, 0);
}

// ---------------------------------------------------------------------------
// K1: weight transpose + cast. Wt[n][k] = bf16(W[k][n]) for 4 E x E matrices.
// ---------------------------------------------------------------------------
__global__ __launch_bounds__(256)
void wcast_kernel(const float* __restrict__ W0, const float* __restrict__ W1,
                  const float* __restrict__ W2, const float* __restrict__ W3,
                  unsigned short* __restrict__ wt) {
  __shared__ float tile[64][65];
  const float* W = (blockIdx.z == 0) ? W0 : (blockIdx.z == 1) ? W1
                 : (blockIdx.z == 2) ? W2 : W3;
  unsigned short* Wt = wt + (size_t)blockIdx.z * (1024u * 1024u);
  int k0 = blockIdx.x * 64, n0 = blockIdx.y * 64;
  int t = threadIdx.x, r = t >> 6, c = t & 63;
#pragma unroll
  for (int i = 0; i < 16; ++i)
    tile[r + i * 4][c] = W[(size_t)(k0 + r + i * 4) * 1024 + n0 + c];
  __syncthreads();
#pragma unroll
  for (int i = 0; i < 16; ++i)
    Wt[(size_t)(n0 + r + i * 4) * 1024 + k0 + c] = bf16_of(tile[c][r + i * 4]);
}

// ---------------------------------------------------------------------------
// K2: fused Q/K/V projection GEMM.
// C[65536x1024] = A(f32)[65536x1024] * Bt^T (+bias).
// z=0: relu -> qw [B,H,S,D]; z=1: relu -> kw; z=2: vw [B,H,D,S] transposed.
// BM=128, BN=256, BK=64, 512 thr / 8 waves (2m x 4n), wave tile 64x64.
// Single-buffer LDS 48KB, both __syncthreads kept.
// Validated ordering principle: only L2-hot glds may be outstanding at a
// barrier; streaming A-loads issue right after barrier 1 so compute covers
// their latency. CHANGE vs r10: B-glds issued BEFORE the A cvt+ds_write
// block, gaining the cvt VALU time as extra glds latency cover.
// LDS rows 128B: phys 16B slot = slot ^ (row&7) on both write & read paths;
// glds keeps linear dest + same involution pre-applied to the global source.
// ---------------------------------------------------------------------------
__global__ __launch_bounds__(512, 4)
void gemm_qkv(const float* __restrict__ Aq, const float* __restrict__ Ak,
              const float* __restrict__ Av, const unsigned short* __restrict__ wt,
              const float* __restrict__ bq, const float* __restrict__ bk,
              const float* __restrict__ bv, unsigned short* __restrict__ qw,
              unsigned short* __restrict__ kw, unsigned short* __restrict__ vw) {
  __shared__ unsigned short ldsA[128 * 64];  // 16KB
  __shared__ unsigned short ldsB[256 * 64];  // 32KB

  int z = blockIdx.z;
  const float* Af = (z == 0) ? Aq : (z == 1) ? Ak : Av;
  const unsigned short* Bt = wt + (size_t)z * 1048576;
  const float* bias = (z == 0) ? bq : (z == 1) ? bk : bv;
  unsigned short* C = (z == 0) ? qw : (z == 1) ? kw : vw;

  int bid = blockIdx.x;
  // XCD swizzle (2048 blocks = 8 XCDs x 256): XCD x gets 64 contiguous
  // m-tiles; the 4 n-tiles of one m-tile are adjacent on that XCD.
  int mt = (bid & 7) * 64 + (bid >> 5);
  int nt = (bid >> 3) & 3;
  int m0 = mt * 128, n0 = nt * 256;

  int tid = threadIdx.x;
  int w = tid >> 6, l = tid & 63;
  int wm = w >> 2, wn = w & 3;
  int li = l & 15, grp = l >> 4;

  f32x4 acc[4][4] = {};

  // glds lane map: chunk c covers 8 rows (1KB); lane l -> row 8c+(l>>3),
  // linear dest slot l&7; source seg pre-swizzled = (l&7)^(row&7).
  int grow = l >> 3;
  int gseg = (l & 7) ^ grow;

  // f32-A staging: thread covers row rA = tid>>2 (0..127), 16 f32 at q*16.
  int rA = tid >> 2, q = tid & 3;

  f32x4 areg[4];
  auto loadA = [&](int kt) {
#pragma unroll
    for (int j = 0; j < 4; ++j)
      areg[j] = *(const f32x4*)(Af + (size_t)(m0 + rA) * 1024 + kt * 64 + q * 16 + j * 4);
  };

  loadA(0);

  for (int kt = 0; kt < 16; ++kt) {
    int k0 = kt * 64;
    // ---- stage B first (glds, L2-hot): latency covered by cvt work below --
#pragma unroll
    for (int i = 0; i < 4; ++i) {
      int c = w * 4 + i;
      gload_lds16(Bt + (size_t)(n0 + 8 * c + grow) * 1024 + k0 + gseg * 8,
                  (char*)ldsB + c * 1024);
    }
    // ---- stage A (cvt + swizzled ds_write; areg loaded one iter ago) ----
    {
      uint4v w0, w1;
      w0[0] = cvt_pk_bf16(areg[0][0], areg[0][1]);
      w0[1] = cvt_pk_bf16(areg[0][2], areg[0][3]);
      w0[2] = cvt_pk_bf16(areg[1][0], areg[1][1]);
      w0[3] = cvt_pk_bf16(areg[1][2], areg[1][3]);
      w1[0] = cvt_pk_bf16(areg[2][0], areg[2][1]);
      w1[1] = cvt_pk_bf16(areg[2][2], areg[2][3]);
      w1[2] = cvt_pk_bf16(areg[3][0], areg[3][1]);
      w1[3] = cvt_pk_bf16(areg[3][2], areg[3][3]);
      *(uint4v*)((char*)ldsA + rA * 128 + (((2 * q)     ^ (rA & 7)) << 4)) = w0;
      *(uint4v*)((char*)ldsA + rA * 128 + (((2 * q + 1) ^ (rA & 7)) << 4)) = w1;
    }
    __syncthreads();   // drains glds (L2-hot, covered) + ds_writes
    // ---- A prefetch for kt+1: issued here, latency covered by compute ----
    if (kt < 15) {
      loadA(kt + 1);
      __builtin_amdgcn_sched_barrier(0);  // don't sink into compute
    }
    // ---- compute: 2 K-subtiles, 16 MFMA each ----
#pragma unroll
    for (int ks = 0; ks < 2; ++ks) {
      short8 af[4], bf[4];
#pragma unroll
      for (int mi = 0; mi < 4; ++mi) {
        int row = wm * 64 + mi * 16 + li;
        af[mi] = *(const short8*)((const char*)ldsA + row * 128 +
                                  (((ks * 4 + grp) ^ (row & 7)) << 4));
      }
#pragma unroll
      for (int ni = 0; ni < 4; ++ni) {
        int row = wn * 64 + ni * 16 + li;
        bf[ni] = *(const short8*)((const char*)ldsB + row * 128 +
                                  (((ks * 4 + grp) ^ (row & 7)) << 4));
      }
#pragma unroll
      for (int mi = 0; mi < 4; ++mi)
#pragma unroll
        for (int ni = 0; ni < 4; ++ni)
          acc[mi][ni] = MFMA_BF16(af[mi], bf[ni], acc[mi][ni]);
    }
    __syncthreads();
  }

  // ---- epilogue ----
  int mrow0 = m0 + wm * 64;   // 64-aligned -> single batch b per wave
  int ncol0 = n0 + wn * 64;   // 64-aligned -> single head h per wave
  float bvv[4];
#pragma unroll
  for (int ni = 0; ni < 4; ++ni) bvv[ni] = bias[ncol0 + ni * 16 + li];

  int b = mrow0 >> 6, h = ncol0 >> 6;
  unsigned short* base = C + (size_t)b * 65536 + (size_t)h * 4096;
  if (z < 2) {  // Q/K: ReLU, [b][h][s][d]
#pragma unroll
    for (int mi = 0; mi < 4; ++mi)
#pragma unroll
      for (int ni = 0; ni < 4; ++ni)
#pragma unroll
        for (int j = 0; j < 4; ++j) {
          float v = acc[mi][ni][j] + bvv[ni];
          v = fmaxf(v, 0.0f);
          base[(mi * 16 + grp * 4 + j) * 64 + ni * 16 + li] = bf16_of(v);
        }
  } else {  // V: transposed [b][h][d][s]
#pragma unroll
    for (int mi = 0; mi < 4; ++mi)
#pragma unroll
      for (int ni = 0; ni < 4; ++ni) {
        uint2v pk;
        pk.x = cvt_pk_bf16(acc[mi][ni][0] + bvv[ni], acc[mi][ni][1] + bvv[ni]);
        pk.y = cvt_pk_bf16(acc[mi][ni][2] + bvv[ni], acc[mi][ni][3] + bvv[ni]);
        *(uint2v*)(base + (ni * 16 + li) * 64 + mi * 16 + grp * 4) = pk;
      }
  }
}

// ---------------------------------------------------------------------------
// K2b: output GEMM. C[65536x1024](f32) = A(bf16) * Bt^T + bo.
// BM=128, BN=256, BK=64, 512 thr / 8 waves (2m x 4n), wave tile 64x64.
// CHANGE vs r10: A (streaming 128MB, L3-at-best) is now reg-staged one iter
// ahead (loads issued after barrier 1, covered by compute) + swizzled
// ds_write -- same validated path as qkv's A, minus the cvt. Only the L2-hot
// B-glds remain outstanding at the barrier drain.
// ---------------------------------------------------------------------------
__global__ __launch_bounds__(512, 4)
void gemm_out(const unsigned short* __restrict__ Ab, const unsigned short* __restrict__ Bt,
              const float* __restrict__ bias, float* __restrict__ C) {
  __shared__ unsigned short ldsA[128 * 64];  // 16KB
  __shared__ unsigned short ldsB[256 * 64];  // 32KB

  int bid = blockIdx.x;
  int mt = (bid & 7) * 64 + (bid >> 5);
  int nt = (bid >> 3) & 3;
  int m0 = mt * 128, n0 = nt * 256;

  int tid = threadIdx.x;
  int w = tid >> 6, l = tid & 63;
  int wm = w >> 2, wn = w & 3;
  int li = l & 15, grp = l >> 4;

  f32x4 acc[4][4] = {};

  int grow = l >> 3;
  int gseg = (l & 7) ^ grow;

  // bf16-A reg staging: thread covers row rA = tid>>2 (0..127), 16 bf16 at
  // cols q*16 (16B segs 2q, 2q+1).
  int rA = tid >> 2, q = tid & 3;

  short8 a0, a1;
  auto loadA = [&](int kt) {
    a0 = *(const short8*)(Ab + (size_t)(m0 + rA) * 1024 + kt * 64 + q * 16);
    a1 = *(const short8*)(Ab + (size_t)(m0 + rA) * 1024 + kt * 64 + q * 16 + 8);
  };

  loadA(0);

  for (int kt = 0; kt < 16; ++kt) {
    int k0 = kt * 64;
    // ---- stage B first (glds, L2-hot weight panel) ----
#pragma unroll
    for (int i = 0; i < 4; ++i) {
      int c = w * 4 + i;
      gload_lds16(Bt + (size_t)(n0 + 8 * c + grow) * 1024 + k0 + gseg * 8,
                  (char*)ldsB + c * 1024);
    }
    // ---- stage A (swizzled ds_write of regs loaded one iter ago) ----
    *(short8*)((char*)ldsA + rA * 128 + (((2 * q)     ^ (rA & 7)) << 4)) = a0;
    *(short8*)((char*)ldsA + rA * 128 + (((2 * q + 1) ^ (rA & 7)) << 4)) = a1;
    __syncthreads();   // drains glds (L2-hot) + ds_writes
    // ---- A prefetch for kt+1 (streaming): covered by compute below ----
    if (kt < 15) {
      loadA(kt + 1);
      __builtin_amdgcn_sched_barrier(0);
    }
    // ---- compute ----
#pragma unroll
    for (int ks = 0; ks < 2; ++ks) {
      short8 af[4], bf[4];
#pragma unroll
      for (int mi = 0; mi < 4; ++mi) {
        int row = wm * 64 + mi * 16 + li;
        af[mi] = *(const short8*)((const char*)ldsA + row * 128 +
                                  (((ks * 4 + grp) ^ (row & 7)) << 4));
      }
#pragma unroll
      for (int ni = 0; ni < 4; ++ni) {
        int row = wn * 64 + ni * 16 + li;
        bf[ni] = *(const short8*)((const char*)ldsB + row * 128 +
                                  (((ks * 4 + grp) ^ (row & 7)) << 4));
      }
#pragma unroll
      for (int mi = 0; mi < 4; ++mi)
#pragma unroll
        for (int ni = 0; ni < 4; ++ni)
          acc[mi][ni] = MFMA_BF16(af[mi], bf[ni], acc[mi][ni]);
    }
    __syncthreads();
  }

  int mrow0 = m0 + wm * 64;
  int ncol0 = n0 + wn * 64;
  float bvv[4];
#pragma unroll
  for (int ni = 0; ni < 4; ++ni) bvv[ni] = bias[ncol0 + ni * 16 + li];
#pragma unroll
  for (int mi = 0; mi < 4; ++mi)
#pragma unroll
    for (int ni = 0; ni < 4; ++ni)
#pragma unroll
      for (int j = 0; j < 4; ++j)
        C[(size_t)(mrow0 + mi * 16 + grp * 4 + j) * 1024 + ncol0 + ni * 16 + li] =
            acc[mi][ni][j] + bvv[ni];
}

// ---------------------------------------------------------------------------
// K3: attention. One wave per (b,h). Q,K: [b][h][s][d] bf16 (ReLU'd, biased),
// V: [b][h][d][s] bf16. Out: [b][s][h][d] bf16.
// ---------------------------------------------------------------------------
__global__ __launch_bounds__(64)
void attn_kernel(const unsigned short* __restrict__ qw,
                 const unsigned short* __restrict__ kw,
                 const unsigned short* __restrict__ vw,
                 unsigned short* __restrict__ aw) {
  __shared__ unsigned short p_lds[64 * 72];
  int bh = blockIdx.x;
  int b = bh >> 4, h = bh & 15;
  int l = threadIdx.x;
  int li = l & 15, grp = l >> 4;
  const unsigned short* qb = qw + (size_t)bh * 4096;
  const unsigned short* kb = kw + (size_t)bh * 4096;
  const unsigned short* vb = vw + (size_t)bh * 4096;

  short8 aq[4][2], bk_[4][2];
#pragma unroll
  for (int mi = 0; mi < 4; ++mi)
#pragma unroll
    for (int ks = 0; ks < 2; ++ks) {
      aq[mi][ks]  = *(const short8*)(qb + (mi * 16 + li) * 64 + ks * 32 + grp * 8);
      bk_[mi][ks] = *(const short8*)(kb + (mi * 16 + li) * 64 + ks * 32 + grp * 8);
    }

  f32x4 sf[4][4];
#pragma unroll
  for (int mi = 0; mi < 4; ++mi)
#pragma unroll
    for (int ni = 0; ni < 4; ++ni) {
      f32x4 t = {};
      t = MFMA_BF16(aq[mi][0], bk_[ni][0], t);
      t = MFMA_BF16(aq[mi][1], bk_[ni][1], t);
      sf[mi][ni] = t;
    }

#pragma unroll
  for (int mi = 0; mi < 4; ++mi) {
#pragma unroll
    for (int j = 0; j < 4; ++j) {
      int row = mi * 16 + grp * 4 + j;
      float mx = -1e30f;
#pragma unroll
      for (int ni = 0; ni < 4; ++ni) {
        int col = ni * 16 + li;
        float v = sf[mi][ni][j] * 0.125f;
        v = (col <= row) ? v : -1e30f;
        sf[mi][ni][j] = v;
        mx = fmaxf(mx, v);
      }
#pragma unroll
      for (int sh = 1; sh < 16; sh <<= 1) mx = fmaxf(mx, __shfl_xor(mx, sh, 64));
      float sum = 0.0f;
#pragma unroll
      for (int ni = 0; ni < 4; ++ni) {
        float e = __expf(sf[mi][ni][j] - mx);
        sf[mi][ni][j] = e;
        sum += e;
      }
#pragma unroll
      for (int sh = 1; sh < 16; sh <<= 1) sum += __shfl_xor(sum, sh, 64);
      float rr = 1.0f / sum;
#pragma unroll
      for (int ni = 0; ni < 4; ++ni) sf[mi][ni][j] *= rr;
    }
  }

#pragma unroll
  for (int mi = 0; mi < 4; ++mi)
#pragma unroll
    for (int ni = 0; ni < 4; ++ni)
#pragma unroll
      for (int j = 0; j < 4; ++j)
        p_lds[(mi * 16 + grp * 4 + j) * 72 + ni * 16 + li] = bf16_of(sf[mi][ni][j]);
  __syncthreads();

  short8 pa[4][2], bv_[4][2];
#pragma unroll
  for (int mi = 0; mi < 4; ++mi)
#pragma unroll
    for (int ks = 0; ks < 2; ++ks)
      pa[mi][ks] = *(const short8*)(p_lds + (mi * 16 + li) * 72 + ks * 32 + grp * 8);
#pragma unroll
  for (int ni = 0; ni < 4; ++ni)
#pragma unroll
    for (int ks = 0; ks < 2; ++ks)
      bv_[ni][ks] = *(const short8*)(vb + (ni * 16 + li) * 64 + ks * 32 + grp * 8);

  f32x4 of[4][4];
#pragma unroll
  for (int mi = 0; mi < 4; ++mi)
#pragma unroll
    for (int ni = 0; ni < 4; ++ni) {
      f32x4 t = {};
      t = MFMA_BF16(pa[mi][0], bv_[ni][0], t);
      t = MFMA_BF16(pa[mi][1], bv_[ni][1], t);
      of[mi][ni] = t;
    }

  unsigned short* ab = aw + (size_t)b * 65536 + (size_t)h * 64;
#pragma unroll
  for (int mi = 0; mi < 4; ++mi)
#pragma unroll
    for (int ni = 0; ni < 4; ++ni)
#pragma unroll
      for (int j = 0; j < 4; ++j)
        ab[(size_t)(mi * 16 + grp * 4 + j) * 1024 + ni * 16 + li] = bf16_of(of[mi][ni][j]);
}

// ---------------------------------------------------------------------------
extern "C" void kernel_launch(void* const* d_in, const int* in_sizes, int n_in,
                              void* d_out, int out_size, void* d_ws, size_t ws_size,
                              hipStream_t stream) {
  (void)in_sizes; (void)n_in; (void)out_size; (void)ws_size;
  const float* query = (const float*)d_in[0];
  const float* key   = (const float*)d_in[1];
  const float* value = (const float*)d_in[2];
  const float* Wq = (const float*)d_in[3];
  const float* bq = (const float*)d_in[4];
  const float* Wk = (const float*)d_in[5];
  const float* bk = (const float*)d_in[6];
  const float* Wv = (const float*)d_in[7];
  const float* bv = (const float*)d_in[8];
  const float* Wo = (const float*)d_in[9];
  const float* bo = (const float*)d_in[10];
  float* out = (float*)d_out;

  unsigned short* wt = (unsigned short*)d_ws;
  const size_t NE = (size_t)67108864;  // B*S*E
  unsigned short* qw = wt + (size_t)4 * 1024 * 1024;
  unsigned short* kw = qw + NE;
  unsigned short* vw = kw + NE;
  unsigned short* aw = vw + NE;

  wcast_kernel<<<dim3(16, 16, 4), 256, 0, stream>>>(Wq, Wk, Wv, Wo, wt);
  gemm_qkv<<<dim3(2048, 1, 3), 512, 0, stream>>>(query, key, value, wt,
                                                 bq, bk, bv, qw, kw, vw);
  attn_kernel<<<dim3(16384), 64, 0, stream>>>(qw, kw, vw, aw);
  gemm_out<<<dim3(2048), 512, 0, stream>>>(aw, wt + (size_t)3 * 1048576, bo, out);
}